// Round 3
// baseline (373.469 us; speedup 1.0000x reference)
//
#include <hip/hip_runtime.h>
#include <math.h>

typedef __attribute__((ext_vector_type(4))) float f32x4;
typedef __attribute__((ext_vector_type(8))) short bf16x8;
typedef __attribute__((ext_vector_type(4))) unsigned short us4;

#define T_SEQ 2048
#define NH 16
#define HD 64
#define CDIM 1024

__device__ __forceinline__ unsigned short f2bf(float f) {
  unsigned int u = __float_as_uint(f);
  u += 0x7fffu + ((u >> 16) & 1u);
  return (unsigned short)(u >> 16);
}

// ---------------- cast x: fp32 -> bf16 ----------------
__global__ __launch_bounds__(256) void cast_x_kernel(const float* __restrict__ src,
                                                     unsigned short* __restrict__ dst,
                                                     int n4) {
  int i = blockIdx.x * 256 + threadIdx.x;
  if (i >= n4) return;
  f32x4 v = reinterpret_cast<const f32x4*>(src)[i];
  us4 o;
#pragma unroll
  for (int j = 0; j < 4; ++j) o[j] = f2bf(v[j]);
  reinterpret_cast<us4*>(dst)[i] = o;
}

// ------------- transpose + cast: W [K][N] fp32 -> W^T [N][K] bf16 -------------
__global__ __launch_bounds__(256) void transpose_cast_kernel(const float* __restrict__ src,
                                                             unsigned short* __restrict__ dst,
                                                             int ldsrc, int lddst) {
  __shared__ float tile[32][33];
  int n0 = blockIdx.x * 32, k0 = blockIdx.y * 32;
  int tx = threadIdx.x, ty = threadIdx.y;  // block (32,8)
#pragma unroll
  for (int r = 0; r < 4; ++r)
    tile[ty + r * 8][tx] = src[(size_t)(k0 + ty + r * 8) * ldsrc + n0 + tx];
  __syncthreads();
#pragma unroll
  for (int r = 0; r < 4; ++r)
    dst[(size_t)(n0 + ty + r * 8) * lddst + k0 + tx] = f2bf(tile[tx][ty + r * 8]);
}

// ---------------- RoPE table: cos/sin [T][32] fp32 ----------------
__global__ __launch_bounds__(256) void rope_table_kernel(float* __restrict__ cost,
                                                         float* __restrict__ sint) {
  int idx = blockIdx.x * 256 + threadIdx.x;  // 2048*32
  int t = idx >> 5, j = idx & 31;
  double invf = pow(10000.0, -(double)j / 32.0);
  double ang = (double)t * invf;
  cost[idx] = (float)cos(ang);
  sint[idx] = (float)sin(ang);
}

// ---------------- GEMM: C[M][N] = A[M][K] * B^T[N][K], bf16 in, fp32 acc ----
// MODE 1: qkv epilogue (RoPE on q/k, scale q, scatter to q/k [BH][T][D], vT [BH][D][T])
// MODE 0: plain fp32 store to out[M][N]
#define LDSP 40  // BK(32) + 8 pad: breaks bank conflicts, keeps 16B alignment

template <int MODE>
__global__ __launch_bounds__(256) void gemm_kernel(
    const unsigned short* __restrict__ A, const unsigned short* __restrict__ Bt,
    int M, int N, int K,
    unsigned short* __restrict__ qo, unsigned short* __restrict__ ko,
    unsigned short* __restrict__ vTo, const float* __restrict__ cost,
    const float* __restrict__ sint, float* __restrict__ out) {
  __shared__ __align__(16) unsigned short As[128][LDSP];
  __shared__ __align__(16) unsigned short Bs[128][LDSP];
  const int tid = threadIdx.x;
  const int lane = tid & 63;
  const int wave = tid >> 6;
  const int wr = wave >> 1, wc = wave & 1;
  const int m0 = blockIdx.y * 128, n0 = blockIdx.x * 128;
  const int lrow = lane & 15, lhi = lane >> 4, lk8 = (lane >> 4) * 8;

  f32x4 zero4 = {0.f, 0.f, 0.f, 0.f};
  f32x4 acc[4][4];
#pragma unroll
  for (int mi = 0; mi < 4; ++mi)
#pragma unroll
    for (int ni = 0; ni < 4; ++ni) acc[mi][ni] = zero4;

  for (int kt = 0; kt < K; kt += 32) {
#pragma unroll
    for (int p = 0; p < 2; ++p) {
      int idx = p * 256 + tid;
      int row = idx >> 2, ch = (idx & 3) * 8;
      bf16x8 av = *reinterpret_cast<const bf16x8*>(&A[(size_t)(m0 + row) * K + kt + ch]);
      bf16x8 bv = *reinterpret_cast<const bf16x8*>(&Bt[(size_t)(n0 + row) * K + kt + ch]);
      *reinterpret_cast<bf16x8*>(&As[row][ch]) = av;
      *reinterpret_cast<bf16x8*>(&Bs[row][ch]) = bv;
    }
    __syncthreads();
    bf16x8 af[4], bfv[4];
#pragma unroll
    for (int i = 0; i < 4; ++i) {
      af[i] = *reinterpret_cast<const bf16x8*>(&As[wr * 64 + i * 16 + lrow][lk8]);
      bfv[i] = *reinterpret_cast<const bf16x8*>(&Bs[wc * 64 + i * 16 + lrow][lk8]);
    }
#pragma unroll
    for (int mi = 0; mi < 4; ++mi)
#pragma unroll
      for (int ni = 0; ni < 4; ++ni)
        acc[mi][ni] =
            __builtin_amdgcn_mfma_f32_16x16x32_bf16(af[mi], bfv[ni], acc[mi][ni], 0, 0, 0);
    __syncthreads();
  }

  if (MODE == 0) {
#pragma unroll
    for (int mi = 0; mi < 4; ++mi)
#pragma unroll
      for (int ni = 0; ni < 4; ++ni) {
        int n = n0 + wc * 64 + ni * 16 + lrow;
#pragma unroll
        for (int r = 0; r < 4; ++r) {
          int m = m0 + wr * 64 + mi * 16 + lhi * 4 + r;
          out[(size_t)m * N + n] = acc[mi][ni][r];
        }
      }
  } else {
#pragma unroll
    for (int mi = 0; mi < 4; ++mi) {
      int mb = m0 + wr * 64 + mi * 16 + lhi * 4;  // 4 consecutive rows (t)
      int b = mb >> 11, tb = mb & (T_SEQ - 1);
#pragma unroll
      for (int ni = 0; ni < 4; ++ni) {
        int n = n0 + wc * 64 + ni * 16 + lrow;
        int sec = n >> 10;          // 0=q 1=k 2=v
        int h = (n >> 6) & 15;
        int d = n & 63;
        if (sec == 2) {
          us4 pk;
#pragma unroll
          for (int r = 0; r < 4; ++r) pk[r] = f2bf(acc[mi][ni][r]);
          *reinterpret_cast<us4*>(&vTo[((size_t)(b * NH + h) * HD + d) * T_SEQ + tb]) = pk;
        } else {
          int dm = d & 31;
          float sgn = (d < 32) ? -1.0f : 1.0f;
          unsigned short* dstp = (sec == 0) ? qo : ko;
#pragma unroll
          for (int r = 0; r < 4; ++r) {
            int t = tb + r;
            float c = cost[t * 32 + dm], s = sint[t * 32 + dm];
            float val = acc[mi][ni][r] * c + sgn * acc[mi][ni ^ 2][r] * s;
            if (sec == 0) val *= 0.125f;  // 1/sqrt(64) folded into q
            dstp[((size_t)(b * NH + h) * T_SEQ + t) * HD + d] = f2bf(val);
          }
        }
      }
    }
  }
}

// ---------------- flash attention, causal ----------------
// 4 waves / 256 threads per block, 128 q rows per block (32/wave), NO K/V LDS
// staging: per-head K+V (512 KB) is L2-resident; each wave reads its MFMA
// fragments directly from global (16B/lane coalesced). No intra-loop barriers
// -> waves fully independent, causally-masked tiles skipped per wave.
// Only per-wave P buffer lives in LDS (18 KB/block) -> 4 blocks/CU.
// XCD swizzle: each XCD owns 8 heads (4 MB K+V = its L2); LPT (big qt first).
#define KVB 64
#define QB 128

__global__ __launch_bounds__(256, 4) void attn_kernel(const unsigned short* __restrict__ qg,
                                                      const unsigned short* __restrict__ kg,
                                                      const unsigned short* __restrict__ vtg,
                                                      unsigned short* __restrict__ att) {
  __shared__ __align__(16) unsigned short P[4][32][72];  // per-wave, padded
  const int tid = threadIdx.x;
  const int lane = tid & 63;
  const int w = tid >> 6;
  const int lrow = lane & 15, lhi = lane >> 4, lk8 = (lane >> 4) * 8;
  // bid -> (head, qtile): xcd = bid&7 owns heads xcd*8..xcd*8+7
  const int bid = (int)blockIdx.x;
  const int xcd = bid & 7, j = bid >> 3;
  const int bh = xcd * 8 + (j >> 4);
  const int qt = 15 - (j & 15);  // heavy blocks first within head
  const int qb = qt * QB;
  const int wq0 = qb + w * 32;  // this wave's first q row
  const unsigned short* qp = qg + (size_t)bh * T_SEQ * HD;
  const unsigned short* kp = kg + (size_t)bh * T_SEQ * HD;
  const unsigned short* vp = vtg + (size_t)bh * T_SEQ * HD;  // [d][t]

  bf16x8 qf[2][2];
#pragma unroll
  for (int mi = 0; mi < 2; ++mi)
#pragma unroll
    for (int kh = 0; kh < 2; ++kh)
      qf[mi][kh] = *reinterpret_cast<const bf16x8*>(
          &qp[(size_t)(wq0 + mi * 16 + lrow) * HD + kh * 32 + lk8]);

  f32x4 zero4 = {0.f, 0.f, 0.f, 0.f};
  f32x4 o[2][4], mrun[2], lrun[2];
#pragma unroll
  for (int mi = 0; mi < 2; ++mi) {
    mrun[mi] = {-3.0e38f, -3.0e38f, -3.0e38f, -3.0e38f};
    lrun[mi] = zero4;
#pragma unroll
    for (int nf = 0; nf < 4; ++nf) o[mi][nf] = zero4;
  }

  const int myt = ((wq0 + 31) >> 6) + 1;  // tiles this wave actually needs
  for (int t = 0; t < myt; ++t) {
    const int kvb = t * KVB;
    f32x4 s[2][4];
#pragma unroll
    for (int ni = 0; ni < 4; ++ni) {
      bf16x8 kf0 =
          *reinterpret_cast<const bf16x8*>(&kp[(size_t)(kvb + ni * 16 + lrow) * HD + lk8]);
      bf16x8 kf1 = *reinterpret_cast<const bf16x8*>(
          &kp[(size_t)(kvb + ni * 16 + lrow) * HD + 32 + lk8]);
#pragma unroll
      for (int mi = 0; mi < 2; ++mi) {
        f32x4 z = zero4;
        z = __builtin_amdgcn_mfma_f32_16x16x32_bf16(qf[mi][0], kf0, z, 0, 0, 0);
        z = __builtin_amdgcn_mfma_f32_16x16x32_bf16(qf[mi][1], kf1, z, 0, 0, 0);
        s[mi][ni] = z;
      }
    }
    if (kvb + 63 > wq0) {  // tile can contain future keys -> mask
#pragma unroll
      for (int mi = 0; mi < 2; ++mi)
#pragma unroll
        for (int ni = 0; ni < 4; ++ni) {
          int key = kvb + ni * 16 + lrow;
#pragma unroll
          for (int r = 0; r < 4; ++r) {
            int qrow = wq0 + mi * 16 + lhi * 4 + r;
            if (key > qrow) s[mi][ni][r] = -1e30f;
          }
        }
    }
#pragma unroll
    for (int mi = 0; mi < 2; ++mi) {
      f32x4 tm = s[mi][0];
#pragma unroll
      for (int ni = 1; ni < 4; ++ni)
#pragma unroll
        for (int r = 0; r < 4; ++r) tm[r] = fmaxf(tm[r], s[mi][ni][r]);
#pragma unroll
      for (int r = 0; r < 4; ++r) {
        float v = tm[r];
        v = fmaxf(v, __shfl_xor(v, 1));
        v = fmaxf(v, __shfl_xor(v, 2));
        v = fmaxf(v, __shfl_xor(v, 4));
        v = fmaxf(v, __shfl_xor(v, 8));
        tm[r] = v;
      }
      f32x4 mnew, alpha, lt = zero4;
#pragma unroll
      for (int r = 0; r < 4; ++r) {
        mnew[r] = fmaxf(mrun[mi][r], tm[r]);
        alpha[r] = __expf(mrun[mi][r] - mnew[r]);
      }
#pragma unroll
      for (int ni = 0; ni < 4; ++ni)
#pragma unroll
        for (int r = 0; r < 4; ++r) {
          float p = __expf(s[mi][ni][r] - mnew[r]);
          s[mi][ni][r] = p;
          lt[r] += p;
        }
#pragma unroll
      for (int r = 0; r < 4; ++r) {
        float v = lt[r];
        v += __shfl_xor(v, 1);
        v += __shfl_xor(v, 2);
        v += __shfl_xor(v, 4);
        v += __shfl_xor(v, 8);
        lrun[mi][r] = lrun[mi][r] * alpha[r] + v;
        mrun[mi][r] = mnew[r];
      }
#pragma unroll
      for (int nf = 0; nf < 4; ++nf)
#pragma unroll
        for (int r = 0; r < 4; ++r) o[mi][nf][r] *= alpha[r];
#pragma unroll
      for (int ni = 0; ni < 4; ++ni)
#pragma unroll
        for (int r = 0; r < 4; ++r)
          P[w][mi * 16 + lhi * 4 + r][ni * 16 + lrow] = f2bf(s[mi][ni][r]);
    }
    // P is per-wave: lockstep wave -> no barrier between write and read
#pragma unroll
    for (int kh = 0; kh < 2; ++kh) {
      bf16x8 pf[2];
#pragma unroll
      for (int mi = 0; mi < 2; ++mi)
        pf[mi] = *reinterpret_cast<const bf16x8*>(&P[w][mi * 16 + lrow][kh * 32 + lk8]);
#pragma unroll
      for (int nf = 0; nf < 4; ++nf) {
        bf16x8 vf = *reinterpret_cast<const bf16x8*>(
            &vp[(size_t)(nf * 16 + lrow) * T_SEQ + kvb + kh * 32 + lk8]);
#pragma unroll
        for (int mi = 0; mi < 2; ++mi)
          o[mi][nf] = __builtin_amdgcn_mfma_f32_16x16x32_bf16(pf[mi], vf, o[mi][nf], 0, 0, 0);
      }
    }
  }

  const int b = bh >> 4, h = bh & 15;
#pragma unroll
  for (int mi = 0; mi < 2; ++mi)
#pragma unroll
    for (int nf = 0; nf < 4; ++nf) {
      f32x4 inv;
#pragma unroll
      for (int r = 0; r < 4; ++r) inv[r] = 1.0f / lrun[mi][r];
#pragma unroll
      for (int r = 0; r < 4; ++r) {
        int t = wq0 + mi * 16 + lhi * 4 + r;
        int d = nf * 16 + lrow;
        att[((size_t)b * T_SEQ + t) * CDIM + h * HD + d] = f2bf(o[mi][nf][r] * inv[r]);
      }
    }
}

extern "C" void kernel_launch(void* const* d_in, const int* in_sizes, int n_in,
                              void* d_out, int out_size, void* d_ws, size_t ws_size,
                              hipStream_t stream) {
  const float* x = (const float*)d_in[0];
  const float* Wq = (const float*)d_in[1];
  const float* Wkv = (const float*)d_in[2];
  const float* Wc = (const float*)d_in[3];
  float* out = (float*)d_out;

  char* ws = (char*)d_ws;
  size_t off = 0;
  auto alloc = [&](size_t bytes) {
    void* p = ws + off;
    off += (bytes + 255) & ~(size_t)255;
    return p;
  };
  const size_t NTOK = 4ull * T_SEQ;            // 8192
  const size_t NELEM = NTOK * CDIM;            // 8388608
  unsigned short* xb = (unsigned short*)alloc(NELEM * 2);   // also reused for att
  unsigned short* WT = (unsigned short*)alloc(3072ull * 1024 * 2);
  unsigned short* WcT = (unsigned short*)alloc(1024ull * 1024 * 2);
  unsigned short* qb = (unsigned short*)alloc(NELEM * 2);
  unsigned short* kb = (unsigned short*)alloc(NELEM * 2);
  unsigned short* vT = (unsigned short*)alloc(NELEM * 2);
  float* cost = (float*)alloc(T_SEQ * 32 * 4);
  float* sint = (float*)alloc(T_SEQ * 32 * 4);
  unsigned short* att = xb;  // xb dead after gemm<1>; reuse for attention output

  cast_x_kernel<<<(int)(NELEM / 4 / 256), 256, 0, stream>>>(x, xb, (int)(NELEM / 4));
  transpose_cast_kernel<<<dim3(32, 32), dim3(32, 8), 0, stream>>>(Wq, WT, 1024, 1024);
  transpose_cast_kernel<<<dim3(64, 32), dim3(32, 8), 0, stream>>>(Wkv, WT + 1024 * 1024, 2048,
                                                                  1024);
  transpose_cast_kernel<<<dim3(32, 32), dim3(32, 8), 0, stream>>>(Wc, WcT, 1024, 1024);
  rope_table_kernel<<<T_SEQ * 32 / 256, 256, 0, stream>>>(cost, sint);

  gemm_kernel<1><<<dim3(3072 / 128, NTOK / 128), 256, 0, stream>>>(
      xb, WT, (int)NTOK, 3072, 1024, qb, kb, vT, cost, sint, nullptr);

  attn_kernel<<<dim3((T_SEQ / QB) * 64), 256, 0, stream>>>(qb, kb, vT, att);

  gemm_kernel<0><<<dim3(1024 / 128, NTOK / 128), 256, 0, stream>>>(
      att, WcT, (int)NTOK, 1024, 1024, nullptr, nullptr, nullptr, nullptr, nullptr, out);
}

// Round 4
// 372.018 us; speedup vs baseline: 1.0039x; 1.0039x over previous
//
#include <hip/hip_runtime.h>
#include <math.h>

typedef __attribute__((ext_vector_type(4))) float f32x4;
typedef __attribute__((ext_vector_type(16))) float f32x16;
typedef __attribute__((ext_vector_type(8))) short bf16x8;
typedef __attribute__((ext_vector_type(4))) unsigned short us4;

#define T_SEQ 2048
#define NH 16
#define HD 64
#define CDIM 1024

__device__ __forceinline__ unsigned short f2bf(float f) {
  unsigned int u = __float_as_uint(f);
  u += 0x7fffu + ((u >> 16) & 1u);
  return (unsigned short)(u >> 16);
}

__device__ __forceinline__ f32x16 zero16() {
  f32x16 z;
#pragma unroll
  for (int i = 0; i < 16; ++i) z[i] = 0.0f;
  return z;
}

// ---------------- cast x: fp32 -> bf16 ----------------
__global__ __launch_bounds__(256) void cast_x_kernel(const float* __restrict__ src,
                                                     unsigned short* __restrict__ dst,
                                                     int n4) {
  int i = blockIdx.x * 256 + threadIdx.x;
  if (i >= n4) return;
  f32x4 v = reinterpret_cast<const f32x4*>(src)[i];
  us4 o;
#pragma unroll
  for (int j = 0; j < 4; ++j) o[j] = f2bf(v[j]);
  reinterpret_cast<us4*>(dst)[i] = o;
}

// ------------- transpose + cast: W [K][N] fp32 -> W^T [N][K] bf16 -------------
__global__ __launch_bounds__(256) void transpose_cast_kernel(const float* __restrict__ src,
                                                             unsigned short* __restrict__ dst,
                                                             int ldsrc, int lddst) {
  __shared__ float tile[32][33];
  int n0 = blockIdx.x * 32, k0 = blockIdx.y * 32;
  int tx = threadIdx.x, ty = threadIdx.y;  // block (32,8)
#pragma unroll
  for (int r = 0; r < 4; ++r)
    tile[ty + r * 8][tx] = src[(size_t)(k0 + ty + r * 8) * ldsrc + n0 + tx];
  __syncthreads();
#pragma unroll
  for (int r = 0; r < 4; ++r)
    dst[(size_t)(n0 + ty + r * 8) * lddst + k0 + tx] = f2bf(tile[tx][ty + r * 8]);
}

// ---------------- RoPE table: cos/sin [T][32] fp32 ----------------
__global__ __launch_bounds__(256) void rope_table_kernel(float* __restrict__ cost,
                                                         float* __restrict__ sint) {
  int idx = blockIdx.x * 256 + threadIdx.x;  // 2048*32
  int t = idx >> 5, j = idx & 31;
  double invf = pow(10000.0, -(double)j / 32.0);
  double ang = (double)t * invf;
  cost[idx] = (float)cos(ang);
  sint[idx] = (float)sin(ang);
}

// ---------------- GEMM: C[M][N] = A[M][K] * B^T[N][K], bf16 in, fp32 acc ----
// MODE 1: qkv epilogue (RoPE on q/k, scale q, scatter to q/k [BH][T][D], vT [BH][D][T])
// MODE 0: plain fp32 store to out[M][N]
#define LDSP 40  // BK(32) + 8 pad: breaks bank conflicts, keeps 16B alignment

template <int MODE>
__global__ __launch_bounds__(256) void gemm_kernel(
    const unsigned short* __restrict__ A, const unsigned short* __restrict__ Bt,
    int M, int N, int K,
    unsigned short* __restrict__ qo, unsigned short* __restrict__ ko,
    unsigned short* __restrict__ vTo, const float* __restrict__ cost,
    const float* __restrict__ sint, float* __restrict__ out) {
  __shared__ __align__(16) unsigned short As[128][LDSP];
  __shared__ __align__(16) unsigned short Bs[128][LDSP];
  const int tid = threadIdx.x;
  const int lane = tid & 63;
  const int wave = tid >> 6;
  const int wr = wave >> 1, wc = wave & 1;
  const int m0 = blockIdx.y * 128, n0 = blockIdx.x * 128;
  const int lrow = lane & 15, lhi = lane >> 4, lk8 = (lane >> 4) * 8;

  f32x4 zero4 = {0.f, 0.f, 0.f, 0.f};
  f32x4 acc[4][4];
#pragma unroll
  for (int mi = 0; mi < 4; ++mi)
#pragma unroll
    for (int ni = 0; ni < 4; ++ni) acc[mi][ni] = zero4;

  for (int kt = 0; kt < K; kt += 32) {
#pragma unroll
    for (int p = 0; p < 2; ++p) {
      int idx = p * 256 + tid;
      int row = idx >> 2, ch = (idx & 3) * 8;
      bf16x8 av = *reinterpret_cast<const bf16x8*>(&A[(size_t)(m0 + row) * K + kt + ch]);
      bf16x8 bv = *reinterpret_cast<const bf16x8*>(&Bt[(size_t)(n0 + row) * K + kt + ch]);
      *reinterpret_cast<bf16x8*>(&As[row][ch]) = av;
      *reinterpret_cast<bf16x8*>(&Bs[row][ch]) = bv;
    }
    __syncthreads();
    bf16x8 af[4], bfv[4];
#pragma unroll
    for (int i = 0; i < 4; ++i) {
      af[i] = *reinterpret_cast<const bf16x8*>(&As[wr * 64 + i * 16 + lrow][lk8]);
      bfv[i] = *reinterpret_cast<const bf16x8*>(&Bs[wc * 64 + i * 16 + lrow][lk8]);
    }
#pragma unroll
    for (int mi = 0; mi < 4; ++mi)
#pragma unroll
      for (int ni = 0; ni < 4; ++ni)
        acc[mi][ni] =
            __builtin_amdgcn_mfma_f32_16x16x32_bf16(af[mi], bfv[ni], acc[mi][ni], 0, 0, 0);
    __syncthreads();
  }

  if (MODE == 0) {
#pragma unroll
    for (int mi = 0; mi < 4; ++mi)
#pragma unroll
      for (int ni = 0; ni < 4; ++ni) {
        int n = n0 + wc * 64 + ni * 16 + lrow;
#pragma unroll
        for (int r = 0; r < 4; ++r) {
          int m = m0 + wr * 64 + mi * 16 + lhi * 4 + r;
          out[(size_t)m * N + n] = acc[mi][ni][r];
        }
      }
  } else {
#pragma unroll
    for (int mi = 0; mi < 4; ++mi) {
      int mb = m0 + wr * 64 + mi * 16 + lhi * 4;  // 4 consecutive rows (t)
      int b = mb >> 11, tb = mb & (T_SEQ - 1);
#pragma unroll
      for (int ni = 0; ni < 4; ++ni) {
        int n = n0 + wc * 64 + ni * 16 + lrow;
        int sec = n >> 10;          // 0=q 1=k 2=v
        int h = (n >> 6) & 15;
        int d = n & 63;
        if (sec == 2) {
          us4 pk;
#pragma unroll
          for (int r = 0; r < 4; ++r) pk[r] = f2bf(acc[mi][ni][r]);
          *reinterpret_cast<us4*>(&vTo[((size_t)(b * NH + h) * HD + d) * T_SEQ + tb]) = pk;
        } else {
          int dm = d & 31;
          float sgn = (d < 32) ? -1.0f : 1.0f;
          unsigned short* dstp = (sec == 0) ? qo : ko;
#pragma unroll
          for (int r = 0; r < 4; ++r) {
            int t = tb + r;
            float c = cost[t * 32 + dm], s = sint[t * 32 + dm];
            float val = acc[mi][ni][r] * c + sgn * acc[mi][ni ^ 2][r] * s;
            if (sec == 0) val *= 0.125f;  // 1/sqrt(64) folded into q
            dstp[((size_t)(b * NH + h) * T_SEQ + t) * HD + d] = f2bf(val);
          }
        }
      }
    }
  }
}

// ---------------- flash attention, causal; 32x32 swapped-QK^T ----------------
// 4 waves/block, 32 q rows per wave. S^T = mfma32x32(K,Q): lane owns ONE query
// (col = lane&31, duplicated across lane halves), 32 key-scores in 2x f32x16.
// Softmax = in-register tree + ONE shfl_xor(32) per reduce; m/l/alpha are
// per-lane scalars. PV: O^T = mfma32x32(V^T, P) -> O cols = queries too, so
// rescale + 1/l are scalar muls. P goes S-layout -> B-operand layout via a
// tiny per-wave LDS roundtrip (8x ds_write_b64 + 4x ds_read_b128 per tile,
// stride 72 halfwords = bank floor). No barriers; waves independent; causal
// tiles skipped per wave; only the LAST tile needs masking (kvb <= wq0).
#define KVB 64
#define QB 128

__global__ __launch_bounds__(256, 3) void attn_kernel(const unsigned short* __restrict__ qg,
                                                      const unsigned short* __restrict__ kg,
                                                      const unsigned short* __restrict__ vtg,
                                                      unsigned short* __restrict__ att) {
  __shared__ __align__(16) unsigned short P[4][32][72];  // per-wave P buffer
  const int tid = threadIdx.x;
  const int lane = tid & 63;
  const int w = tid >> 6;
  const int l31 = lane & 31, hi = lane >> 5;
  const int hi8 = hi * 8;
  // bid -> (head, qtile): xcd = bid&7 owns heads xcd*8..xcd*8+7
  const int bid = (int)blockIdx.x;
  const int xcd = bid & 7, j = bid >> 3;
  const int bh = xcd * 8 + (j >> 4);
  const int qt = 15 - (j & 15);  // heavy blocks first within head
  const int wq0 = qt * QB + w * 32;
  const int qrow = wq0 + l31;  // this lane's query row
  const unsigned short* qp = qg + (size_t)bh * T_SEQ * HD;
  const unsigned short* kp = kg + (size_t)bh * T_SEQ * HD;
  const unsigned short* vp = vtg + (size_t)bh * T_SEQ * HD;  // [d][t]

  bf16x8 qf[4];  // Q B-frags: Q[qrow][ks*16 + hi*8 + e]
#pragma unroll
  for (int ks = 0; ks < 4; ++ks)
    qf[ks] = *reinterpret_cast<const bf16x8*>(&qp[(size_t)qrow * HD + ks * 16 + hi8]);

  f32x16 oA = zero16(), oB = zero16();  // O^T: rows d 0-31 / 32-63, col = qrow
  float mrun = -3.0e38f, lrun = 0.0f;

  const int myt = ((wq0 + 31) >> 6) + 1;
  for (int t = 0; t < myt; ++t) {
    const int kvb = t * KVB;
    // ---- QK^T (swapped): S^T rows = keys, col = qrow ----
    bf16x8 kfa[4], kfb[4];
#pragma unroll
    for (int ks = 0; ks < 4; ++ks) {
      kfa[ks] =
          *reinterpret_cast<const bf16x8*>(&kp[(size_t)(kvb + l31) * HD + ks * 16 + hi8]);
      kfb[ks] =
          *reinterpret_cast<const bf16x8*>(&kp[(size_t)(kvb + 32 + l31) * HD + ks * 16 + hi8]);
    }
    f32x16 sA = zero16(), sB = zero16();
#pragma unroll
    for (int ks = 0; ks < 4; ++ks) {
      sA = __builtin_amdgcn_mfma_f32_32x32x16_bf16(kfa[ks], qf[ks], sA, 0, 0, 0);
      sB = __builtin_amdgcn_mfma_f32_32x32x16_bf16(kfb[ks], qf[ks], sB, 0, 0, 0);
    }
    // ---- causal mask (only final tile can contain future keys) ----
    if (t == myt - 1) {
#pragma unroll
      for (int r = 0; r < 16; ++r) {
        int keyA = kvb + (r & 3) + 8 * (r >> 2) + 4 * hi;
        if (keyA > qrow) sA[r] = -1e30f;
        if (keyA + 32 > qrow) sB[r] = -1e30f;
      }
    }
    // ---- in-register online softmax (per-lane scalars) ----
    float tr[16];
#pragma unroll
    for (int i = 0; i < 16; ++i) tr[i] = fmaxf(sA[i], sB[i]);
#pragma unroll
    for (int i = 0; i < 8; ++i) tr[i] = fmaxf(tr[i], tr[i + 8]);
#pragma unroll
    for (int i = 0; i < 4; ++i) tr[i] = fmaxf(tr[i], tr[i + 4]);
    float tm = fmaxf(fmaxf(tr[0], tr[1]), fmaxf(tr[2], tr[3]));
    tm = fmaxf(tm, __shfl_xor(tm, 32));  // merge lane halves (same query)
    float mnew = fmaxf(mrun, tm);
    float alpha = __expf(mrun - mnew);
#pragma unroll
    for (int i = 0; i < 16; ++i) {
      sA[i] = __expf(sA[i] - mnew);
      sB[i] = __expf(sB[i] - mnew);
    }
    float sr[16];
#pragma unroll
    for (int i = 0; i < 16; ++i) sr[i] = sA[i] + sB[i];
#pragma unroll
    for (int i = 0; i < 8; ++i) sr[i] += sr[i + 8];
#pragma unroll
    for (int i = 0; i < 4; ++i) sr[i] += sr[i + 4];
    float lsum = (sr[0] + sr[1]) + (sr[2] + sr[3]);
    lsum += __shfl_xor(lsum, 32);
    lrun = lrun * alpha + lsum;
    mrun = mnew;
#pragma unroll
    for (int i = 0; i < 16; ++i) {
      oA[i] *= alpha;
      oB[i] *= alpha;
    }
    // ---- P: S-layout -> [q][key] in LDS (per-wave, no barrier) ----
#pragma unroll
    for (int g = 0; g < 4; ++g) {
      us4 pa, pb;
#pragma unroll
      for (int jj = 0; jj < 4; ++jj) {
        pa[jj] = f2bf(sA[4 * g + jj]);
        pb[jj] = f2bf(sB[4 * g + jj]);
      }
      *reinterpret_cast<us4*>(&P[w][l31][g * 8 + 4 * hi]) = pa;
      *reinterpret_cast<us4*>(&P[w][l31][32 + g * 8 + 4 * hi]) = pb;
    }
    // ---- PV: O^T += mfma(V^T, P) ----
#pragma unroll
    for (int ks = 0; ks < 4; ++ks) {
      bf16x8 pf = *reinterpret_cast<const bf16x8*>(&P[w][l31][ks * 16 + hi8]);
      bf16x8 vfa = *reinterpret_cast<const bf16x8*>(
          &vp[(size_t)l31 * T_SEQ + kvb + ks * 16 + hi8]);
      bf16x8 vfb = *reinterpret_cast<const bf16x8*>(
          &vp[(size_t)(32 + l31) * T_SEQ + kvb + ks * 16 + hi8]);
      oA = __builtin_amdgcn_mfma_f32_32x32x16_bf16(vfa, pf, oA, 0, 0, 0);
      oB = __builtin_amdgcn_mfma_f32_32x32x16_bf16(vfb, pf, oB, 0, 0, 0);
    }
  }

  const int b = bh >> 4, h = bh & 15;
  const float inv = 1.0f / lrun;
  const size_t obase = ((size_t)b * T_SEQ + qrow) * CDIM + h * HD;
#pragma unroll
  for (int g = 0; g < 4; ++g) {
    us4 pa, pb;
#pragma unroll
    for (int jj = 0; jj < 4; ++jj) {
      pa[jj] = f2bf(oA[4 * g + jj] * inv);
      pb[jj] = f2bf(oB[4 * g + jj] * inv);
    }
    *reinterpret_cast<us4*>(&att[obase + g * 8 + 4 * hi]) = pa;
    *reinterpret_cast<us4*>(&att[obase + 32 + g * 8 + 4 * hi]) = pb;
  }
}

extern "C" void kernel_launch(void* const* d_in, const int* in_sizes, int n_in,
                              void* d_out, int out_size, void* d_ws, size_t ws_size,
                              hipStream_t stream) {
  const float* x = (const float*)d_in[0];
  const float* Wq = (const float*)d_in[1];
  const float* Wkv = (const float*)d_in[2];
  const float* Wc = (const float*)d_in[3];
  float* out = (float*)d_out;

  char* ws = (char*)d_ws;
  size_t off = 0;
  auto alloc = [&](size_t bytes) {
    void* p = ws + off;
    off += (bytes + 255) & ~(size_t)255;
    return p;
  };
  const size_t NTOK = 4ull * T_SEQ;            // 8192
  const size_t NELEM = NTOK * CDIM;            // 8388608
  unsigned short* xb = (unsigned short*)alloc(NELEM * 2);   // also reused for att
  unsigned short* WT = (unsigned short*)alloc(3072ull * 1024 * 2);
  unsigned short* WcT = (unsigned short*)alloc(1024ull * 1024 * 2);
  unsigned short* qb = (unsigned short*)alloc(NELEM * 2);
  unsigned short* kb = (unsigned short*)alloc(NELEM * 2);
  unsigned short* vT = (unsigned short*)alloc(NELEM * 2);
  float* cost = (float*)alloc(T_SEQ * 32 * 4);
  float* sint = (float*)alloc(T_SEQ * 32 * 4);
  unsigned short* att = xb;  // xb dead after gemm<1>; reuse for attention output

  cast_x_kernel<<<(int)(NELEM / 4 / 256), 256, 0, stream>>>(x, xb, (int)(NELEM / 4));
  transpose_cast_kernel<<<dim3(32, 32), dim3(32, 8), 0, stream>>>(Wq, WT, 1024, 1024);
  transpose_cast_kernel<<<dim3(64, 32), dim3(32, 8), 0, stream>>>(Wkv, WT + 1024 * 1024, 2048,
                                                                  1024);
  transpose_cast_kernel<<<dim3(32, 32), dim3(32, 8), 0, stream>>>(Wc, WcT, 1024, 1024);
  rope_table_kernel<<<T_SEQ * 32 / 256, 256, 0, stream>>>(cost, sint);

  gemm_kernel<1><<<dim3(3072 / 128, NTOK / 128), 256, 0, stream>>>(
      xb, WT, (int)NTOK, 3072, 1024, qb, kb, vT, cost, sint, nullptr);

  attn_kernel<<<dim3((T_SEQ / QB) * 64), 256, 0, stream>>>(qb, kb, vT, att);

  gemm_kernel<0><<<dim3(1024 / 128, NTOK / 128), 256, 0, stream>>>(
      att, WcT, (int)NTOK, 1024, 1024, nullptr, nullptr, nullptr, nullptr, nullptr, out);
}

// Round 5
// 240.626 us; speedup vs baseline: 1.5521x; 1.5460x over previous
//
#include <hip/hip_runtime.h>
#include <math.h>

typedef __attribute__((ext_vector_type(4))) float f32x4;
typedef __attribute__((ext_vector_type(16))) float f32x16;
typedef __attribute__((ext_vector_type(8))) short bf16x8;
typedef __attribute__((ext_vector_type(4))) unsigned short us4;

#define T_SEQ 2048
#define NH 16
#define HD 64
#define CDIM 1024

__device__ __forceinline__ unsigned short f2bf(float f) {
  unsigned int u = __float_as_uint(f);
  u += 0x7fffu + ((u >> 16) & 1u);
  return (unsigned short)(u >> 16);
}

__device__ __forceinline__ f32x16 zero16() {
  f32x16 z;
#pragma unroll
  for (int i = 0; i < 16; ++i) z[i] = 0.0f;
  return z;
}

// ---------------- cast x: fp32 -> bf16 ----------------
__global__ __launch_bounds__(256) void cast_x_kernel(const float* __restrict__ src,
                                                     unsigned short* __restrict__ dst,
                                                     int n4) {
  int i = blockIdx.x * 256 + threadIdx.x;
  if (i >= n4) return;
  f32x4 v = reinterpret_cast<const f32x4*>(src)[i];
  us4 o;
#pragma unroll
  for (int j = 0; j < 4; ++j) o[j] = f2bf(v[j]);
  reinterpret_cast<us4*>(dst)[i] = o;
}

// ------------- transpose + cast: W [K][N] fp32 -> W^T [N][K] bf16 -------------
__global__ __launch_bounds__(256) void transpose_cast_kernel(const float* __restrict__ src,
                                                             unsigned short* __restrict__ dst,
                                                             int ldsrc, int lddst) {
  __shared__ float tile[32][33];
  int n0 = blockIdx.x * 32, k0 = blockIdx.y * 32;
  int tx = threadIdx.x, ty = threadIdx.y;  // block (32,8)
#pragma unroll
  for (int r = 0; r < 4; ++r)
    tile[ty + r * 8][tx] = src[(size_t)(k0 + ty + r * 8) * ldsrc + n0 + tx];
  __syncthreads();
#pragma unroll
  for (int r = 0; r < 4; ++r)
    dst[(size_t)(n0 + ty + r * 8) * lddst + k0 + tx] = f2bf(tile[tx][ty + r * 8]);
}

// ---------------- RoPE table: cos/sin [T][32] fp32 ----------------
__global__ __launch_bounds__(256) void rope_table_kernel(float* __restrict__ cost,
                                                         float* __restrict__ sint) {
  int idx = blockIdx.x * 256 + threadIdx.x;  // 2048*32
  int t = idx >> 5, j = idx & 31;
  double invf = pow(10000.0, -(double)j / 32.0);
  double ang = (double)t * invf;
  cost[idx] = (float)cos(ang);
  sint[idx] = (float)sin(ang);
}

// ---------------- GEMM: C[M][N] = A[M][K] * B^T[N][K], bf16 in, fp32 acc ----
// MODE 1: qkv epilogue with RoPE; q/k/v stored in FRAGMENT-MAJOR layouts so the
//   attention kernel's loads are lane-contiguous (coalesced 4-line loads):
//   QF/KF[bh][blk32][ks][lane][8]: holds X[blk*32+l31][ks*16+hi*8+e], lane=hi*32+l31
//   VF[bh][t64][dgrp][ks][lane][8]: holds V[t64*64+ks*16+hi*8+e][dgrp*32+l31]
// MODE 0: plain fp32 store to out[M][N]
#define LDSP 40  // BK(32) + 8 pad: breaks bank conflicts, keeps 16B alignment

template <int MODE>
__global__ __launch_bounds__(256) void gemm_kernel(
    const unsigned short* __restrict__ A, const unsigned short* __restrict__ Bt,
    int M, int N, int K,
    unsigned short* __restrict__ qo, unsigned short* __restrict__ ko,
    unsigned short* __restrict__ vTo, const float* __restrict__ cost,
    const float* __restrict__ sint, float* __restrict__ out) {
  __shared__ __align__(16) unsigned short As[128][LDSP];
  __shared__ __align__(16) unsigned short Bs[128][LDSP];
  const int tid = threadIdx.x;
  const int lane = tid & 63;
  const int wave = tid >> 6;
  const int wr = wave >> 1, wc = wave & 1;
  const int m0 = blockIdx.y * 128, n0 = blockIdx.x * 128;
  const int lrow = lane & 15, lhi = lane >> 4, lk8 = (lane >> 4) * 8;

  f32x4 zero4 = {0.f, 0.f, 0.f, 0.f};
  f32x4 acc[4][4];
#pragma unroll
  for (int mi = 0; mi < 4; ++mi)
#pragma unroll
    for (int ni = 0; ni < 4; ++ni) acc[mi][ni] = zero4;

  for (int kt = 0; kt < K; kt += 32) {
#pragma unroll
    for (int p = 0; p < 2; ++p) {
      int idx = p * 256 + tid;
      int row = idx >> 2, ch = (idx & 3) * 8;
      bf16x8 av = *reinterpret_cast<const bf16x8*>(&A[(size_t)(m0 + row) * K + kt + ch]);
      bf16x8 bv = *reinterpret_cast<const bf16x8*>(&Bt[(size_t)(n0 + row) * K + kt + ch]);
      *reinterpret_cast<bf16x8*>(&As[row][ch]) = av;
      *reinterpret_cast<bf16x8*>(&Bs[row][ch]) = bv;
    }
    __syncthreads();
    bf16x8 af[4], bfv[4];
#pragma unroll
    for (int i = 0; i < 4; ++i) {
      af[i] = *reinterpret_cast<const bf16x8*>(&As[wr * 64 + i * 16 + lrow][lk8]);
      bfv[i] = *reinterpret_cast<const bf16x8*>(&Bs[wc * 64 + i * 16 + lrow][lk8]);
    }
#pragma unroll
    for (int mi = 0; mi < 4; ++mi)
#pragma unroll
      for (int ni = 0; ni < 4; ++ni)
        acc[mi][ni] =
            __builtin_amdgcn_mfma_f32_16x16x32_bf16(af[mi], bfv[ni], acc[mi][ni], 0, 0, 0);
    __syncthreads();
  }

  if (MODE == 0) {
#pragma unroll
    for (int mi = 0; mi < 4; ++mi)
#pragma unroll
      for (int ni = 0; ni < 4; ++ni) {
        int n = n0 + wc * 64 + ni * 16 + lrow;
#pragma unroll
        for (int r = 0; r < 4; ++r) {
          int m = m0 + wr * 64 + mi * 16 + lhi * 4 + r;
          out[(size_t)m * N + n] = acc[mi][ni][r];
        }
      }
  } else {
#pragma unroll
    for (int mi = 0; mi < 4; ++mi) {
      int mb = m0 + wr * 64 + mi * 16 + lhi * 4;  // 4 consecutive rows (t)
      int b = mb >> 11, tb = mb & (T_SEQ - 1);
#pragma unroll
      for (int ni = 0; ni < 4; ++ni) {
        int n = n0 + wc * 64 + ni * 16 + lrow;
        int sec = n >> 10;          // 0=q 1=k 2=v
        int h = (n >> 6) & 15;
        int d = n & 63;
        int bh_ = b * NH + h;
        if (sec == 2) {
          // VF[bh][t64][dgrp][ks][lane][8], us4 over t=tb..tb+3 (e contiguous)
          int t64 = tb >> 6, ks = (tb >> 4) & 3, hiv = (tb >> 3) & 1, e0 = tb & 7;
          int dgrp = d >> 5, lanev = hiv * 32 + (d & 31);
          us4 pk;
#pragma unroll
          for (int r = 0; r < 4; ++r) pk[r] = f2bf(acc[mi][ni][r]);
          size_t addr =
              ((((size_t)bh_ * 32 + t64) * 2 + dgrp) * 4 + ks) * 512 + lanev * 8 + e0;
          *reinterpret_cast<us4*>(&vTo[addr]) = pk;
        } else {
          int dm = d & 31;
          float sgn = (d < 32) ? -1.0f : 1.0f;
          unsigned short* dstp = (sec == 0) ? qo : ko;
          int ks = d >> 4, hiq = (d >> 3) & 1, e = d & 7;
#pragma unroll
          for (int r = 0; r < 4; ++r) {
            int t = tb + r;
            float c = cost[t * 32 + dm], s = sint[t * 32 + dm];
            float val = acc[mi][ni][r] * c + sgn * acc[mi][ni ^ 2][r] * s;
            if (sec == 0) val *= 0.125f;  // 1/sqrt(64) folded into q
            int blk = t >> 5, lane_ = hiq * 32 + (t & 31);
            dstp[(((size_t)bh_ * 64 + blk) * 4 + ks) * 512 + lane_ * 8 + e] = f2bf(val);
          }
        }
      }
    }
  }
}

// ---------------- flash attention, causal; 32x32 swapped-QK^T ----------------
// Same compute structure as R4 (lane owns one query; in-register softmax with
// one shfl_xor(32) per reduce; PV via O^T = mfma(V^T, P)). Memory now reads
// fragment-major KF/QF/VF: every load is base + lane*16B -> coalesced.
// V loads hoisted before softmax (latency hides under it). P crosses to
// B-operand layout via per-wave LDS roundtrip (no barriers anywhere).
#define KVB 64
#define QB 128

__global__ __launch_bounds__(256, 3) void attn_kernel(const unsigned short* __restrict__ qg,
                                                      const unsigned short* __restrict__ kg,
                                                      const unsigned short* __restrict__ vtg,
                                                      unsigned short* __restrict__ att) {
  __shared__ __align__(16) unsigned short P[4][32][72];  // per-wave P buffer
  const int tid = threadIdx.x;
  const int lane = tid & 63;
  const int w = tid >> 6;
  const int l31 = lane & 31, hi = lane >> 5;
  // bid -> (head, qtile): xcd = bid&7 owns heads xcd*8..xcd*8+7
  const int bid = (int)blockIdx.x;
  const int xcd = bid & 7, j = bid >> 3;
  const int bh = xcd * 8 + (j >> 4);
  const int qt = 15 - (j & 15);  // heavy blocks first within head
  const int wq0 = qt * QB + w * 32;
  const int qrow = wq0 + l31;  // this lane's query row
  const unsigned short* qfp = qg + (size_t)bh * 131072;
  const unsigned short* kfp = kg + (size_t)bh * 131072;
  const unsigned short* vfp = vtg + (size_t)bh * 131072;

  bf16x8 qf[4];  // QF[bh][qblk][ks][lane]
  const int qblk = qt * 4 + w;
#pragma unroll
  for (int ks = 0; ks < 4; ++ks)
    qf[ks] = *reinterpret_cast<const bf16x8*>(&qfp[((size_t)qblk * 4 + ks) * 512 + lane * 8]);

  f32x16 oA = zero16(), oB = zero16();  // O^T: rows d 0-31 / 32-63, col = qrow
  float mrun = -3.0e38f, lrun = 0.0f;

  const int myt = ((wq0 + 31) >> 6) + 1;
  for (int t = 0; t < myt; ++t) {
    const int kvb = t * KVB;
    // ---- coalesced fragment loads: K tile (2 blk32 groups) + V tile ----
    bf16x8 kfa[4], kfb[4], vfa[4], vfb[4];
#pragma unroll
    for (int ks = 0; ks < 4; ++ks) {
      kfa[ks] = *reinterpret_cast<const bf16x8*>(
          &kfp[((size_t)(2 * t) * 4 + ks) * 512 + lane * 8]);
      kfb[ks] = *reinterpret_cast<const bf16x8*>(
          &kfp[((size_t)(2 * t + 1) * 4 + ks) * 512 + lane * 8]);
      vfa[ks] = *reinterpret_cast<const bf16x8*>(
          &vfp[((size_t)(2 * t) * 4 + ks) * 512 + lane * 8]);
      vfb[ks] = *reinterpret_cast<const bf16x8*>(
          &vfp[((size_t)(2 * t + 1) * 4 + ks) * 512 + lane * 8]);
    }
    // ---- QK^T (swapped): S^T rows = keys, col = qrow ----
    f32x16 sA = zero16(), sB = zero16();
#pragma unroll
    for (int ks = 0; ks < 4; ++ks) {
      sA = __builtin_amdgcn_mfma_f32_32x32x16_bf16(kfa[ks], qf[ks], sA, 0, 0, 0);
      sB = __builtin_amdgcn_mfma_f32_32x32x16_bf16(kfb[ks], qf[ks], sB, 0, 0, 0);
    }
    // ---- causal mask (only final tile can contain future keys) ----
    if (t == myt - 1) {
#pragma unroll
      for (int r = 0; r < 16; ++r) {
        int keyA = kvb + (r & 3) + 8 * (r >> 2) + 4 * hi;
        if (keyA > qrow) sA[r] = -1e30f;
        if (keyA + 32 > qrow) sB[r] = -1e30f;
      }
    }
    // ---- in-register online softmax (per-lane scalars) ----
    float tr[16];
#pragma unroll
    for (int i = 0; i < 16; ++i) tr[i] = fmaxf(sA[i], sB[i]);
#pragma unroll
    for (int i = 0; i < 8; ++i) tr[i] = fmaxf(tr[i], tr[i + 8]);
#pragma unroll
    for (int i = 0; i < 4; ++i) tr[i] = fmaxf(tr[i], tr[i + 4]);
    float tm = fmaxf(fmaxf(tr[0], tr[1]), fmaxf(tr[2], tr[3]));
    tm = fmaxf(tm, __shfl_xor(tm, 32));  // merge lane halves (same query)
    float mnew = fmaxf(mrun, tm);
    float alpha = __expf(mrun - mnew);
#pragma unroll
    for (int i = 0; i < 16; ++i) {
      sA[i] = __expf(sA[i] - mnew);
      sB[i] = __expf(sB[i] - mnew);
    }
    float sr[16];
#pragma unroll
    for (int i = 0; i < 16; ++i) sr[i] = sA[i] + sB[i];
#pragma unroll
    for (int i = 0; i < 8; ++i) sr[i] += sr[i + 8];
#pragma unroll
    for (int i = 0; i < 4; ++i) sr[i] += sr[i + 4];
    float lsum = (sr[0] + sr[1]) + (sr[2] + sr[3]);
    lsum += __shfl_xor(lsum, 32);
    lrun = lrun * alpha + lsum;
    mrun = mnew;
#pragma unroll
    for (int i = 0; i < 16; ++i) {
      oA[i] *= alpha;
      oB[i] *= alpha;
    }
    // ---- P: S-layout -> [q][key] in LDS (per-wave, no barrier) ----
#pragma unroll
    for (int g = 0; g < 4; ++g) {
      us4 pa, pb;
#pragma unroll
      for (int jj = 0; jj < 4; ++jj) {
        pa[jj] = f2bf(sA[4 * g + jj]);
        pb[jj] = f2bf(sB[4 * g + jj]);
      }
      *reinterpret_cast<us4*>(&P[w][l31][g * 8 + 4 * hi]) = pa;
      *reinterpret_cast<us4*>(&P[w][l31][32 + g * 8 + 4 * hi]) = pb;
    }
    // ---- PV: O^T += mfma(V^T, P) ----
#pragma unroll
    for (int ks = 0; ks < 4; ++ks) {
      bf16x8 pf = *reinterpret_cast<const bf16x8*>(&P[w][l31][ks * 16 + hi * 8]);
      oA = __builtin_amdgcn_mfma_f32_32x32x16_bf16(vfa[ks], pf, oA, 0, 0, 0);
      oB = __builtin_amdgcn_mfma_f32_32x32x16_bf16(vfb[ks], pf, oB, 0, 0, 0);
    }
  }

  const int b = bh >> 4, h = bh & 15;
  const float inv = 1.0f / lrun;
  const size_t obase = ((size_t)b * T_SEQ + qrow) * CDIM + h * HD;
#pragma unroll
  for (int g = 0; g < 4; ++g) {
    us4 pa, pb;
#pragma unroll
    for (int jj = 0; jj < 4; ++jj) {
      pa[jj] = f2bf(oA[4 * g + jj] * inv);
      pb[jj] = f2bf(oB[4 * g + jj] * inv);
    }
    *reinterpret_cast<us4*>(&att[obase + g * 8 + 4 * hi]) = pa;
    *reinterpret_cast<us4*>(&att[obase + 32 + g * 8 + 4 * hi]) = pb;
  }
}

extern "C" void kernel_launch(void* const* d_in, const int* in_sizes, int n_in,
                              void* d_out, int out_size, void* d_ws, size_t ws_size,
                              hipStream_t stream) {
  const float* x = (const float*)d_in[0];
  const float* Wq = (const float*)d_in[1];
  const float* Wkv = (const float*)d_in[2];
  const float* Wc = (const float*)d_in[3];
  float* out = (float*)d_out;

  char* ws = (char*)d_ws;
  size_t off = 0;
  auto alloc = [&](size_t bytes) {
    void* p = ws + off;
    off += (bytes + 255) & ~(size_t)255;
    return p;
  };
  const size_t NTOK = 4ull * T_SEQ;            // 8192
  const size_t NELEM = NTOK * CDIM;            // 8388608
  unsigned short* xb = (unsigned short*)alloc(NELEM * 2);   // also reused for att
  unsigned short* WT = (unsigned short*)alloc(3072ull * 1024 * 2);
  unsigned short* WcT = (unsigned short*)alloc(1024ull * 1024 * 2);
  unsigned short* qb = (unsigned short*)alloc(NELEM * 2);
  unsigned short* kb = (unsigned short*)alloc(NELEM * 2);
  unsigned short* vT = (unsigned short*)alloc(NELEM * 2);
  float* cost = (float*)alloc(T_SEQ * 32 * 4);
  float* sint = (float*)alloc(T_SEQ * 32 * 4);
  unsigned short* att = xb;  // xb dead after gemm<1>; reuse for attention output

  cast_x_kernel<<<(int)(NELEM / 4 / 256), 256, 0, stream>>>(x, xb, (int)(NELEM / 4));
  transpose_cast_kernel<<<dim3(32, 32), dim3(32, 8), 0, stream>>>(Wq, WT, 1024, 1024);
  transpose_cast_kernel<<<dim3(64, 32), dim3(32, 8), 0, stream>>>(Wkv, WT + 1024 * 1024, 2048,
                                                                  1024);
  transpose_cast_kernel<<<dim3(32, 32), dim3(32, 8), 0, stream>>>(Wc, WcT, 1024, 1024);
  rope_table_kernel<<<T_SEQ * 32 / 256, 256, 0, stream>>>(cost, sint);

  gemm_kernel<1><<<dim3(3072 / 128, NTOK / 128), 256, 0, stream>>>(
      xb, WT, (int)NTOK, 3072, 1024, qb, kb, vT, cost, sint, nullptr);

  attn_kernel<<<dim3((T_SEQ / QB) * 64), 256, 0, stream>>>(qb, kb, vT, att);

  gemm_kernel<0><<<dim3(1024 / 128, NTOK / 128), 256, 0, stream>>>(
      att, WcT, (int)NTOK, 1024, 1024, nullptr, nullptr, nullptr, nullptr, nullptr, out);
}